// Round 1
// baseline (249.248 us; speedup 1.0000x reference)
//
#include <hip/hip_runtime.h>

// Problem constants (reference: B=1, S=4096, D_EMB=768, H=12, D_QKV=64, INV_TEMP=1)
#define S 4096
#define E 768
#define NH 12
#define DH 64
// 1/sqrt(64) * log2(e): softmax computed in base 2 (exp2), scale folded into Q
#define QSCALE (0.125f * 1.44269504f)
#define KSPLIT 4

typedef __bf16 bf16;
typedef __bf16 bf16x2 __attribute__((ext_vector_type(2)));
typedef __bf16 bf16x4 __attribute__((ext_vector_type(4)));
typedef __bf16 bf16x8 __attribute__((ext_vector_type(8)));
typedef float  f32x4  __attribute__((ext_vector_type(4)));
typedef unsigned int u32;
typedef u32 u32x2 __attribute__((ext_vector_type(2)));
typedef u32 u32x4 __attribute__((ext_vector_type(4)));

#define MFMA(a, b, c) __builtin_amdgcn_mfma_f32_16x16x32_bf16(a, b, c, 0, 0, 0)

// async global->LDS, 16B per lane. Global address is PER-LANE; LDS dest is
// wave-uniform base (HW adds lane*16).
__device__ __forceinline__ void async16(const bf16* g, bf16* l) {
  __builtin_amdgcn_global_load_lds(
      (const __attribute__((address_space(1))) void*)g,
      (__attribute__((address_space(3))) void*)l, 16, 0, 0);
}

// ---------------------------------------------------------------------------
// Fused prologue: blocks 0..2303 transpose-cast the 4 weight matrices;
// blocks 2304.. cast q/k/v inputs to bf16.
// ---------------------------------------------------------------------------
__global__ __launch_bounds__(256) void prologue(const float* __restrict__ q_in,
                                                const float* __restrict__ k_in,
                                                const float* __restrict__ v_in,
                                                const float* __restrict__ w0,
                                                const float* __restrict__ w1,
                                                const float* __restrict__ w2,
                                                const float* __restrict__ w3,
                                                bf16* __restrict__ qb,
                                                bf16* __restrict__ kb,
                                                bf16* __restrict__ vb,
                                                bf16* __restrict__ t0,
                                                bf16* __restrict__ t1,
                                                bf16* __restrict__ t2,
                                                bf16* __restrict__ t3) {
  const int bid = blockIdx.x, tid = threadIdx.x;
  if (bid < 2304) {
    const int z = bid / 576, rem = bid % 576;
    const int bx = rem % 24, by = rem / 24;
    const float* W = z == 0 ? w0 : (z == 1 ? w1 : (z == 2 ? w2 : w3));
    bf16* Wt = z == 0 ? t0 : (z == 1 ? t1 : (z == 2 ? t2 : t3));
    __shared__ float t[32][33];
    const int tx = tid & 31, ty = tid >> 5;
    for (int j = ty; j < 32; j += 8)
      t[j][tx] = W[(by * 32 + j) * E + bx * 32 + tx];
    __syncthreads();
    for (int j = ty; j < 32; j += 8)
      Wt[(bx * 32 + j) * E + by * 32 + tx] = (bf16)t[tx][j];
  } else {
    const int b2 = bid - 2304;
    const int z = b2 / 3072, r2 = b2 % 3072;
    const float* in = z == 0 ? q_in : (z == 1 ? k_in : v_in);
    bf16* out = z == 0 ? qb : (z == 1 ? kb : vb);
    const int i = r2 * 1024 + tid * 4;
    float4 v = *(const float4*)(in + i);
    bf16x4 o = { (bf16)v.x, (bf16)v.y, (bf16)v.z, (bf16)v.w };
    *(bf16x4*)(out + i) = o;
  }
}

// ---------------------------------------------------------------------------
// QKV projection GEMM, 128x128 tile, batched over blockIdx.z (z=0 Q, 1 K, 2 V).
// async16 staging, BK=32, 4 waves 2x2, each 64x64. Epilogue stages C in LDS
// (stride 136; V transposed), then fully-coalesced writes:
//   z=0: Q*QSCALE -> [NH][S][DH] row-major
//   z=1: K -> fragment-linear: frag i of 64-key tile at tilebase+i*512+lane*8
//        i=nb*2+j holds K[t*64+nb*16+l16][j*32+quad*8+e]
//   z=2: V -> fragment-linear: i=db*2+jv holds V[t*64+jv*32+quad*8+e][db*16+l16]
// ---------------------------------------------------------------------------
__global__ __launch_bounds__(256) void gemm128(const bf16* __restrict__ A0,
                                               const bf16* __restrict__ A1,
                                               const bf16* __restrict__ A2,
                                               const bf16* __restrict__ B0,
                                               const bf16* __restrict__ B1,
                                               const bf16* __restrict__ B2,
                                               const float* __restrict__ bias0,
                                               const float* __restrict__ bias1,
                                               const float* __restrict__ bias2,
                                               bf16* __restrict__ C0,
                                               bf16* __restrict__ C1,
                                               bf16* __restrict__ C2) {
  __shared__ __align__(16) bf16 smem[128 * 136];
  bf16* Asm = smem;
  bf16* Bsm = smem + 4096;
  bf16* Cs  = smem;

  const int z = blockIdx.z;
  const bf16* A  = z == 0 ? A0 : (z == 1 ? A1 : A2);
  const bf16* Bt = z == 0 ? B0 : (z == 1 ? B1 : B2);
  const float* bias = z == 0 ? bias0 : (z == 1 ? bias1 : bias2);

  const int tid = threadIdx.x;
  const int wv = tid >> 6, lane = tid & 63;
  const int quad = lane >> 4, l16 = lane & 15;
  const int m0 = blockIdx.x * 128, n0 = blockIdx.y * 128;
  const int wm = (wv >> 1) * 64, wn = (wv & 1) * 64;
  const int srow = lane >> 2, scol = (lane & 3) * 8;

  f32x4 acc[4][4] = {};

  for (int k0 = 0; k0 < E; k0 += 32) {
#pragma unroll
    for (int j = 0; j < 2; j++) {
      const int ch = wv * 2 + j;  // wave-uniform
      async16(&A[(size_t)(m0 + ch * 16 + srow) * E + k0 + scol], &Asm[ch * 512]);
      async16(&Bt[(size_t)(n0 + ch * 16 + srow) * E + k0 + scol], &Bsm[ch * 512]);
    }
    __syncthreads();
    bf16x8 af[4], bfv[4];
#pragma unroll
    for (int mi = 0; mi < 4; mi++)
      af[mi] = *(const bf16x8*)&Asm[(wm + mi * 16 + l16) * 32 + quad * 8];
#pragma unroll
    for (int ni = 0; ni < 4; ni++)
      bfv[ni] = *(const bf16x8*)&Bsm[(wn + ni * 16 + l16) * 32 + quad * 8];
#pragma unroll
    for (int mi = 0; mi < 4; mi++)
#pragma unroll
      for (int ni = 0; ni < 4; ni++)
        acc[mi][ni] = MFMA(af[mi], bfv[ni], acc[mi][ni]);
    __syncthreads();
  }

  // ---- stage C tile into LDS ----
  const float scale = (z == 0) ? QSCALE : 1.0f;
#pragma unroll
  for (int mi = 0; mi < 4; mi++) {
#pragma unroll
    for (int ni = 0; ni < 4; ni++) {
      const int nl = wn + ni * 16 + l16;
      const float bv = bias[n0 + nl];
#pragma unroll
      for (int r = 0; r < 4; r++) {
        const int ml = wm + mi * 16 + quad * 4 + r;
        const float v = (acc[mi][ni][r] + bv) * scale;
        if (z == 2) Cs[nl * 136 + ml] = (bf16)v;   // V transposed [d][key]
        else        Cs[ml * 136 + nl] = (bf16)v;
      }
    }
  }
  __syncthreads();

  // ---- coalesced writeout ----
  if (z == 0) {
    const int e = lane & 7;
#pragma unroll
    for (int p = 0; p < 8; p++) {
      const int hr = p * 32 + wv * 8 + (lane >> 3);
      const int r = hr >> 1, hf = hr & 1;
      bf16x8 c = *(const bf16x8*)&Cs[r * 136 + hf * 64 + e * 8];
      *(bf16x8*)(C0 + (size_t)((n0 >> 6) + hf) * S * DH + (size_t)(m0 + r) * DH + e * 8) = c;
    }
  } else {
    bf16* dst = (z == 1) ? C1 : C2;
#pragma unroll
    for (int p = 0; p < 8; p++) {
      const int cid = p * 4 + wv;
      const int reg = cid >> 3;
      const int i = cid & 7;
      const int h_l = reg >> 1, tile = reg & 1;
      bf16x8 c;
      if (z == 1) {
        const int row = tile * 64 + (i >> 1) * 16 + l16;
        const int col = h_l * 64 + (i & 1) * 32 + quad * 8;
        c = *(const bf16x8*)&Cs[row * 136 + col];
      } else {
        const int nl = h_l * 64 + (i >> 1) * 16 + l16;
        const int ml = tile * 64 + (i & 1) * 32 + quad * 8;
        c = *(const bf16x8*)&Cs[nl * 136 + ml];
      }
      *(bf16x8*)(dst + (size_t)((n0 >> 6) + h_l) * S * DH +
                 (size_t)((m0 >> 6) + tile) * 4096 + i * 512 + lane * 8) = c;
    }
  }
}

// ---------------------------------------------------------------------------
// Flash attention, OPERAND-SWAPPED: S^T = K·Q^T, O^T = V^T·P^T.
// NEW: the P redistribution (S^T C-layout -> PV B-fragment) is done entirely
// in registers with v_permlane32_swap + v_permlane16_swap — the LDS round
// trip (16 ds_write_b64 + 8 ds_read_b128 + 5M bank-conflict cycles/dispatch)
// is gone from the main loop; LDS is now epilogue-only.
//   Derivation: S^T block (kb,qb): lane(qs,l16) reg r holds
//   P[qrow=qb*16+l16][key=16kb+4qs+r]. Pack exp2'd pairs into dwords
//   X[kb][j] = keys {16kb+4qs+2j, +1}. PV B-frag needs lane(qt,l16) dword w
//   of bp[qb][jc] = keys {32jc+8qt+2w, +1}  ->  kb=2jc+(qt>>1),
//   qs=(2qt+(w>>1))&3, j=w&1: a pure quad-permutation of whole dwords.
//   permlane32_swap(A,B) -> [A0,A1,B0,B1],[A2,A3,B2,B3]; then
//   permlane16_swap of those -> [A0,A2,B0,B2],[A1,A3,B1,B3] = W_{j}, W_{2+j}.
// Row-sums = ones·P^T on the MFMA pipe (unchanged).
// m=4 (64 q-rows/wave), ksplit=4, max-free base-2 softmax.
// Epilogue: O^T routed through the (now otherwise unused) LDS region ->
// coalesced stores. setprio(1) wraps the rowsum+PV MFMA cluster (T5).
// ---------------------------------------------------------------------------
__global__ __launch_bounds__(256, 3) void attn(const bf16* __restrict__ Q,
                                               const bf16* __restrict__ Kf,
                                               const bf16* __restrict__ Vf,
                                               bf16* __restrict__ Op0,
                                               bf16* __restrict__ Op1,
                                               bf16* __restrict__ Op2,
                                               bf16* __restrict__ Op3,
                                               float* __restrict__ Lp) {
  __shared__ __align__(16) bf16 P2[4][64][72];   // epilogue staging only; 36,864 B
  const int h = blockIdx.y, ks = blockIdx.z;
  const int tid = threadIdx.x;
  const int wave = tid >> 6, lane = tid & 63;
  const int quad = lane >> 4, l16 = lane & 15;
  const int q0 = blockIdx.x * 256 + wave * 64;

  const bf16* Qh = Q + (size_t)h * S * DH;
  const bf16* kbase = Kf + (size_t)h * S * DH + (size_t)ks * (S / KSPLIT) * DH + lane * 8;
  const bf16* vbase = Vf + (size_t)h * S * DH + (size_t)ks * (S / KSPLIT) * DH + lane * 8;
  bf16* Op = ks == 0 ? Op0 : (ks == 1 ? Op1 : (ks == 2 ? Op2 : Op3));

  // Q fragments (B-operand): [qb][k-chunk]
  bf16x8 aq[4][2];
#pragma unroll
  for (int qb = 0; qb < 4; qb++)
#pragma unroll
    for (int j = 0; j < 2; j++)
      aq[qb][j] = *(const bf16x8*)&Qh[(size_t)(q0 + qb * 16 + l16) * DH + j * 32 + quad * 8];

  bf16x8 ones;
#pragma unroll
  for (int e = 0; e < 8; e++) ones[e] = (bf16)1.0f;

  f32x4 o[4][4] = {};   // [db][qb] : O^T accumulation (row=d, col=qrow)
  f32x4 ol[4] = {};     // row-sums L[qrow] via ones·P^T
  const f32x4 fz = {};  // shared zero C-operand (no per-block v_mov re-init)

  bf16* Pw = &P2[wave][0][0];

  const int T = (S / KSPLIT) / 64;  // 16
  for (int t = 0; t < T; ++t) {
    const bf16* kp = kbase + (size_t)t * 4096;
    bf16x8 kr[8];
#pragma unroll
    for (int i = 0; i < 8; i++) kr[i] = *(const bf16x8*)(kp + i * 512);

    // S^T = K·Q^T per (kb,qb); exp2; pack to dwords; permlane-redistribute
    bf16x8 bp[4][2];
#pragma unroll
    for (int qb = 0; qb < 4; qb++) {
      u32 X[4][2];
#pragma unroll
      for (int kb = 0; kb < 4; kb++) {
        f32x4 st = MFMA(kr[kb * 2], aq[qb][0], fz);
        st = MFMA(kr[kb * 2 + 1], aq[qb][1], st);
        bf16x2 e0 = { (bf16)__builtin_exp2f(st[0]), (bf16)__builtin_exp2f(st[1]) };
        bf16x2 e1 = { (bf16)__builtin_exp2f(st[2]), (bf16)__builtin_exp2f(st[3]) };
        X[kb][0] = __builtin_bit_cast(u32, e0);
        X[kb][1] = __builtin_bit_cast(u32, e1);
      }
#pragma unroll
      for (int jc = 0; jc < 2; jc++) {
        u32x2 a0 = __builtin_amdgcn_permlane32_swap(X[2 * jc][0], X[2 * jc + 1][0], false, false);
        u32x2 b0 = __builtin_amdgcn_permlane16_swap(a0[0], a0[1], false, false);
        u32x2 a1 = __builtin_amdgcn_permlane32_swap(X[2 * jc][1], X[2 * jc + 1][1], false, false);
        u32x2 b1 = __builtin_amdgcn_permlane16_swap(a1[0], a1[1], false, false);
        u32x4 wv = { b0[0], b1[0], b0[1], b1[1] };  // {W0,W1,W2,W3}
        bp[qb][jc] = __builtin_bit_cast(bf16x8, wv);
      }
    }

    __builtin_amdgcn_s_setprio(1);
    // L[qrow] += ones · P^T  (MFMA pipe)
#pragma unroll
    for (int qb = 0; qb < 4; qb++) {
      ol[qb] = MFMA(ones, bp[qb][0], ol[qb]);
      ol[qb] = MFMA(ones, bp[qb][1], ol[qb]);
    }

    // O^T += V^T · P^T
    const bf16* vp = vbase + (size_t)t * 4096;
#pragma unroll
    for (int db = 0; db < 4; db++) {
      bf16x8 v0 = *(const bf16x8*)(vp + (db * 2) * 512);
      bf16x8 v1 = *(const bf16x8*)(vp + (db * 2 + 1) * 512);
#pragma unroll
      for (int qb = 0; qb < 4; qb++) {
        o[db][qb] = MFMA(v0, bp[qb][0], o[db][qb]);
        o[db][qb] = MFMA(v1, bp[qb][1], o[db][qb]);
      }
    }
    __builtin_amdgcn_s_setprio(0);
  }

  // ---- epilogue ----
  // partial row-sums: ol[qb] C-layout col=l16=qrow (all rows identical)
  float* Lph = Lp + (size_t)(ks * NH + h) * S;
  if (quad == 0) {
#pragma unroll
    for (int qb = 0; qb < 4; qb++)
      Lph[q0 + qb * 16 + l16] = ol[qb][0];
  }
  // O^T -> LDS (per-wave region, wave-internal ordering)
#pragma unroll
  for (int db = 0; db < 4; db++)
#pragma unroll
    for (int qb = 0; qb < 4; qb++) {
      bf16x4 pk;
#pragma unroll
      for (int r = 0; r < 4; r++) pk[r] = (bf16)o[db][qb][r];
      *(bf16x4*)&Pw[(qb * 16 + l16) * 72 + db * 16 + quad * 4] = pk;
    }
  // coalesced stores: 8 rows/inst, 128B contiguous per row segment
  {
    const int rr = lane >> 3, ee = (lane & 7) * 8;
#pragma unroll
    for (int p = 0; p < 8; p++) {
      const int row = p * 8 + rr;
      bf16x8 c = *(const bf16x8*)&Pw[row * 72 + ee];
      *(bf16x8*)(Op + (size_t)(q0 + row) * E + h * DH + ee) = c;
    }
  }
}

// ---------------------------------------------------------------------------
// Combine ksplit partials: Obf = (Op0+Op1+Op2+Op3) / (L0+L1+L2+L3).
// Obf aliases Op0 (same-thread element-wise read-then-write — safe).
// ---------------------------------------------------------------------------
__global__ __launch_bounds__(256) void combine(const bf16* __restrict__ Op0,
                                               const bf16* __restrict__ Op1,
                                               const bf16* __restrict__ Op2,
                                               const bf16* __restrict__ Op3,
                                               const float* __restrict__ Lp,
                                               bf16* __restrict__ Obf) {
  const int i8 = blockIdx.x * 256 + threadIdx.x;
  const size_t base = (size_t)i8 * 8;
  const int row = (int)(base / E), c = (int)(base % E);
  const int h = c >> 6;
  const float l = Lp[(size_t)h * S + row] + Lp[(size_t)(NH + h) * S + row] +
                  Lp[(size_t)(2 * NH + h) * S + row] + Lp[(size_t)(3 * NH + h) * S + row];
  const float rl = 1.0f / l;
  bf16x8 a = *(const bf16x8*)(Op0 + base);
  bf16x8 b = *(const bf16x8*)(Op1 + base);
  bf16x8 cc = *(const bf16x8*)(Op2 + base);
  bf16x8 d = *(const bf16x8*)(Op3 + base);
  bf16x8 o;
#pragma unroll
  for (int e = 0; e < 8; e++)
    o[e] = (bf16)((((float)a[e] + (float)b[e]) + ((float)cc[e] + (float)d[e])) * rl);
  *(bf16x8*)(Obf + base) = o;
}

// ---------------------------------------------------------------------------
// Final projection: C[S][E] fp32 = A[S][E]bf16 @ WoT^T + b_o.
// 64x64 tile, BK=64 (k-halves stacked in LDS: one barrier pair per 64-K,
// halving barrier drains vs BK=32). grid (64,12) = 768 blocks = 3/CU.
// ---------------------------------------------------------------------------
__global__ __launch_bounds__(256) void gemm64(const bf16* __restrict__ A,
                                              const bf16* __restrict__ Bt,
                                              const float* __restrict__ bias,
                                              float* __restrict__ C) {
  __shared__ __align__(16) bf16 Asm[2][64 * 32];
  __shared__ __align__(16) bf16 Bsm[2][64 * 32];
  const int tid = threadIdx.x;
  const int wv = tid >> 6, lane = tid & 63;
  const int quad = lane >> 4, l16 = lane & 15;
  const int m0 = blockIdx.x * 64, n0 = blockIdx.y * 64;
  const int srow = lane >> 2, scol = (lane & 3) * 8;

  f32x4 acc[4] = {};

  for (int k0 = 0; k0 < E; k0 += 64) {
#pragma unroll
    for (int jc = 0; jc < 2; jc++) {
      async16(&A[(size_t)(m0 + wv * 16 + srow) * E + k0 + jc * 32 + scol], &Asm[jc][wv * 512]);
      async16(&Bt[(size_t)(n0 + wv * 16 + srow) * E + k0 + jc * 32 + scol], &Bsm[jc][wv * 512]);
    }
    __syncthreads();
#pragma unroll
    for (int jc = 0; jc < 2; jc++) {
      bf16x8 af = *(const bf16x8*)&Asm[jc][(wv * 16 + l16) * 32 + quad * 8];
#pragma unroll
      for (int ni = 0; ni < 4; ni++) {
        bf16x8 bfr = *(const bf16x8*)&Bsm[jc][(ni * 16 + l16) * 32 + quad * 8];
        acc[ni] = MFMA(af, bfr, acc[ni]);
      }
    }
    __syncthreads();
  }

  const int row0 = m0 + wv * 16 + quad * 4;
#pragma unroll
  for (int ni = 0; ni < 4; ni++) {
    const int col = n0 + ni * 16 + l16;
    const float bv = bias[col];
#pragma unroll
    for (int r = 0; r < 4; r++)
      C[(size_t)(row0 + r) * E + col] = acc[ni][r] + bv;
  }
}

// ---------------------------------------------------------------------------
// Launch
// ---------------------------------------------------------------------------
extern "C" void kernel_launch(void* const* d_in, const int* in_sizes, int n_in,
                              void* d_out, int out_size, void* d_ws, size_t ws_size,
                              hipStream_t stream) {
  (void)in_sizes; (void)n_in; (void)out_size; (void)ws_size;
  const float* q_in = (const float*)d_in[0];
  const float* k_in = (const float*)d_in[1];
  const float* v_in = (const float*)d_in[2];
  const float* W_q  = (const float*)d_in[3];
  const float* b_q  = (const float*)d_in[4];
  const float* W_k  = (const float*)d_in[5];
  const float* b_k  = (const float*)d_in[6];
  const float* W_v  = (const float*)d_in[7];
  const float* b_v  = (const float*)d_in[8];
  const float* W_o  = (const float*)d_in[9];
  const float* b_o  = (const float*)d_in[10];

  const size_t SE2 = (size_t)S * E * 2;   // bf16 [S][E] bytes
  const size_t EE2 = (size_t)E * E * 2;
  char* ws = (char*)d_ws;
  bf16* qb  = (bf16*)(ws);                    // dead after gemm128 -> Op1
  bf16* kb  = (bf16*)(ws + SE2);              // dead after gemm128 -> Op2
  bf16* vb  = (bf16*)(ws + 2 * SE2);          // dead after gemm128 -> Op3
  bf16* WqT = (bf16*)(ws + 3 * SE2);          // dead after gemm128 -> Lp
  bf16* WkT = (bf16*)(ws + 3 * SE2 + EE2);
  bf16* WvT = (bf16*)(ws + 3 * SE2 + 2 * EE2);
  bf16* WoT = (bf16*)(ws + 3 * SE2 + 3 * EE2);
  bf16* Qh  = (bf16*)(ws + 3 * SE2 + 4 * EE2);
  bf16* Kf  = (bf16*)(ws + 4 * SE2 + 4 * EE2);
  bf16* Vf  = (bf16*)(ws + 5 * SE2 + 4 * EE2);
  bf16* Obf = (bf16*)(ws + 6 * SE2 + 4 * EE2);  // also Op0
  bf16* Op1 = qb;
  bf16* Op2 = kb;
  bf16* Op3 = vb;
  float* Lp = (float*)WqT;                    // [4][NH][S] fp32 = 786 KB < EE2
  // total ws: 7*SE2 + 4*EE2 = 48,758,784 bytes

  prologue<<<dim3(2304 + 3 * 3072), 256, 0, stream>>>(
      q_in, k_in, v_in, W_q, W_k, W_v, W_o, qb, kb, vb, WqT, WkT, WvT, WoT);

  gemm128<<<dim3(S / 128, E / 128, 3), 256, 0, stream>>>(
      qb, kb, vb, WqT, WkT, WvT, b_q, b_k, b_v, Qh, Kf, Vf);

  attn<<<dim3(S / 256, NH, KSPLIT), 256, 0, stream>>>(Qh, Kf, Vf, Obf, Op1, Op2, Op3, Lp);

  combine<<<dim3(S * E / 2048), 256, 0, stream>>>(Obf, Op1, Op2, Op3, Lp, Obf);

  gemm64<<<dim3(S / 64, E / 64), 256, 0, stream>>>(Obf, WoT, b_o, (float*)d_out);
}

// Round 2
// 240.937 us; speedup vs baseline: 1.0345x; 1.0345x over previous
//
#include <hip/hip_runtime.h>

// Problem constants (reference: B=1, S=4096, D_EMB=768, H=12, D_QKV=64, INV_TEMP=1)
#define S 4096
#define E 768
#define NH 12
#define DH 64
// 1/sqrt(64) * log2(e): softmax computed in base 2 (exp2), scale folded into Q
#define QSCALE (0.125f * 1.44269504f)
#define KSPLIT 4

typedef __bf16 bf16;
typedef __bf16 bf16x4 __attribute__((ext_vector_type(4)));
typedef __bf16 bf16x8 __attribute__((ext_vector_type(8)));
typedef float  f32x4  __attribute__((ext_vector_type(4)));

#define MFMA(a, b, c) __builtin_amdgcn_mfma_f32_16x16x32_bf16(a, b, c, 0, 0, 0)

// async global->LDS, 16B per lane. Global address is PER-LANE; LDS dest is
// wave-uniform base (HW adds lane*16).
__device__ __forceinline__ void async16(const bf16* g, bf16* l) {
  __builtin_amdgcn_global_load_lds(
      (const __attribute__((address_space(1))) void*)g,
      (__attribute__((address_space(3))) void*)l, 16, 0, 0);
}

// ---------------------------------------------------------------------------
// Fused prologue: blocks 0..2303 transpose-cast the 4 weight matrices;
// blocks 2304.. cast q/k/v inputs to bf16.
// ---------------------------------------------------------------------------
__global__ __launch_bounds__(256) void prologue(const float* __restrict__ q_in,
                                                const float* __restrict__ k_in,
                                                const float* __restrict__ v_in,
                                                const float* __restrict__ w0,
                                                const float* __restrict__ w1,
                                                const float* __restrict__ w2,
                                                const float* __restrict__ w3,
                                                bf16* __restrict__ qb,
                                                bf16* __restrict__ kb,
                                                bf16* __restrict__ vb,
                                                bf16* __restrict__ t0,
                                                bf16* __restrict__ t1,
                                                bf16* __restrict__ t2,
                                                bf16* __restrict__ t3) {
  const int bid = blockIdx.x, tid = threadIdx.x;
  if (bid < 2304) {
    const int z = bid / 576, rem = bid % 576;
    const int bx = rem % 24, by = rem / 24;
    const float* W = z == 0 ? w0 : (z == 1 ? w1 : (z == 2 ? w2 : w3));
    bf16* Wt = z == 0 ? t0 : (z == 1 ? t1 : (z == 2 ? t2 : t3));
    __shared__ float t[32][33];
    const int tx = tid & 31, ty = tid >> 5;
    for (int j = ty; j < 32; j += 8)
      t[j][tx] = W[(by * 32 + j) * E + bx * 32 + tx];
    __syncthreads();
    for (int j = ty; j < 32; j += 8)
      Wt[(bx * 32 + j) * E + by * 32 + tx] = (bf16)t[tx][j];
  } else {
    const int b2 = bid - 2304;
    const int z = b2 / 3072, r2 = b2 % 3072;
    const float* in = z == 0 ? q_in : (z == 1 ? k_in : v_in);
    bf16* out = z == 0 ? qb : (z == 1 ? kb : vb);
    const int i = r2 * 1024 + tid * 4;
    float4 v = *(const float4*)(in + i);
    bf16x4 o = { (bf16)v.x, (bf16)v.y, (bf16)v.z, (bf16)v.w };
    *(bf16x4*)(out + i) = o;
  }
}

// ---------------------------------------------------------------------------
// QKV projection GEMM, 128x128 tile, batched over blockIdx.z (z=0 Q, 1 K, 2 V).
// async16 staging, BK=32, 4 waves 2x2, each 64x64. Epilogue stages C in LDS
// (stride 136; V transposed), then fully-coalesced writes:
//   z=0: Q*QSCALE -> [NH][S][DH] row-major
//   z=1: K -> fragment-linear: frag i of 64-key tile at tilebase+i*512+lane*8
//        i=nb*2+j holds K[t*64+nb*16+l16][j*32+quad*8+e]
//   z=2: V -> fragment-linear: i=db*2+jv holds V[t*64+jv*32+quad*8+e][db*16+l16]
// ---------------------------------------------------------------------------
__global__ __launch_bounds__(256) void gemm128(const bf16* __restrict__ A0,
                                               const bf16* __restrict__ A1,
                                               const bf16* __restrict__ A2,
                                               const bf16* __restrict__ B0,
                                               const bf16* __restrict__ B1,
                                               const bf16* __restrict__ B2,
                                               const float* __restrict__ bias0,
                                               const float* __restrict__ bias1,
                                               const float* __restrict__ bias2,
                                               bf16* __restrict__ C0,
                                               bf16* __restrict__ C1,
                                               bf16* __restrict__ C2) {
  __shared__ __align__(16) bf16 smem[128 * 136];
  bf16* Asm = smem;
  bf16* Bsm = smem + 4096;
  bf16* Cs  = smem;

  const int z = blockIdx.z;
  const bf16* A  = z == 0 ? A0 : (z == 1 ? A1 : A2);
  const bf16* Bt = z == 0 ? B0 : (z == 1 ? B1 : B2);
  const float* bias = z == 0 ? bias0 : (z == 1 ? bias1 : bias2);

  const int tid = threadIdx.x;
  const int wv = tid >> 6, lane = tid & 63;
  const int quad = lane >> 4, l16 = lane & 15;
  const int m0 = blockIdx.x * 128, n0 = blockIdx.y * 128;
  const int wm = (wv >> 1) * 64, wn = (wv & 1) * 64;
  const int srow = lane >> 2, scol = (lane & 3) * 8;

  f32x4 acc[4][4] = {};

  for (int k0 = 0; k0 < E; k0 += 32) {
#pragma unroll
    for (int j = 0; j < 2; j++) {
      const int ch = wv * 2 + j;  // wave-uniform
      async16(&A[(size_t)(m0 + ch * 16 + srow) * E + k0 + scol], &Asm[ch * 512]);
      async16(&Bt[(size_t)(n0 + ch * 16 + srow) * E + k0 + scol], &Bsm[ch * 512]);
    }
    __syncthreads();
    bf16x8 af[4], bfv[4];
#pragma unroll
    for (int mi = 0; mi < 4; mi++)
      af[mi] = *(const bf16x8*)&Asm[(wm + mi * 16 + l16) * 32 + quad * 8];
#pragma unroll
    for (int ni = 0; ni < 4; ni++)
      bfv[ni] = *(const bf16x8*)&Bsm[(wn + ni * 16 + l16) * 32 + quad * 8];
#pragma unroll
    for (int mi = 0; mi < 4; mi++)
#pragma unroll
      for (int ni = 0; ni < 4; ni++)
        acc[mi][ni] = MFMA(af[mi], bfv[ni], acc[mi][ni]);
    __syncthreads();
  }

  // ---- stage C tile into LDS ----
  const float scale = (z == 0) ? QSCALE : 1.0f;
#pragma unroll
  for (int mi = 0; mi < 4; mi++) {
#pragma unroll
    for (int ni = 0; ni < 4; ni++) {
      const int nl = wn + ni * 16 + l16;
      const float bv = bias[n0 + nl];
#pragma unroll
      for (int r = 0; r < 4; r++) {
        const int ml = wm + mi * 16 + quad * 4 + r;
        const float v = (acc[mi][ni][r] + bv) * scale;
        if (z == 2) Cs[nl * 136 + ml] = (bf16)v;   // V transposed [d][key]
        else        Cs[ml * 136 + nl] = (bf16)v;
      }
    }
  }
  __syncthreads();

  // ---- coalesced writeout ----
  if (z == 0) {
    const int e = lane & 7;
#pragma unroll
    for (int p = 0; p < 8; p++) {
      const int hr = p * 32 + wv * 8 + (lane >> 3);
      const int r = hr >> 1, hf = hr & 1;
      bf16x8 c = *(const bf16x8*)&Cs[r * 136 + hf * 64 + e * 8];
      *(bf16x8*)(C0 + (size_t)((n0 >> 6) + hf) * S * DH + (size_t)(m0 + r) * DH + e * 8) = c;
    }
  } else {
    bf16* dst = (z == 1) ? C1 : C2;
#pragma unroll
    for (int p = 0; p < 8; p++) {
      const int cid = p * 4 + wv;
      const int reg = cid >> 3;
      const int i = cid & 7;
      const int h_l = reg >> 1, tile = reg & 1;
      bf16x8 c;
      if (z == 1) {
        const int row = tile * 64 + (i >> 1) * 16 + l16;
        const int col = h_l * 64 + (i & 1) * 32 + quad * 8;
        c = *(const bf16x8*)&Cs[row * 136 + col];
      } else {
        const int nl = h_l * 64 + (i >> 1) * 16 + l16;
        const int ml = tile * 64 + (i & 1) * 32 + quad * 8;
        c = *(const bf16x8*)&Cs[nl * 136 + ml];
      }
      *(bf16x8*)(dst + (size_t)((n0 >> 6) + h_l) * S * DH +
                 (size_t)((m0 >> 6) + tile) * 4096 + i * 512 + lane * 8) = c;
    }
  }
}

// ---------------------------------------------------------------------------
// Flash attention, OPERAND-SWAPPED: S^T = K·Q^T, O^T = V^T·P^T.
// Round-2 change vs the 95.6us baseline: OCCUPANCY. Per-wave Q-block halved
// 64->32 rows (qb in {0,1}): accumulators o[4][2]+ol[2] = 40 AGPR (was 80),
// aq/bp halve -> ~110 unified regs -> 4+ waves/SIMD (was 164 -> 3). Grid.x
// doubles to 32 (1536 blocks = 6/CU available; was 768 = exactly 3/CU).
// LDS epilogue staging halves to [4][32][72] = 18.4KB. launch_bounds(256,4).
// Plus T1 XCD swizzle: flat block id remapped so each XCD owns 6 contiguous
// (h,ks) slices (ks fastest) -> per-XCD working set Q(2x512KB)+K/V(1.5MB)
// ~2.5MB < 4MB L2 -> K/V HBM re-fetch drops.
// P redistribution via per-wave LDS round-trip (round-1 permlane experiment
// regressed: LDS cost was hidden; permlane added critical-path VALU).
// ---------------------------------------------------------------------------
__global__ __launch_bounds__(256, 4) void attn(const bf16* __restrict__ Q,
                                               const bf16* __restrict__ Kf,
                                               const bf16* __restrict__ Vf,
                                               bf16* __restrict__ Op0,
                                               bf16* __restrict__ Op1,
                                               bf16* __restrict__ Op2,
                                               bf16* __restrict__ Op3,
                                               float* __restrict__ Lp) {
  __shared__ __align__(16) bf16 P2[4][32][72];   // per-wave P[qrow][key]; 18,432 B
  // XCD-aware remap: hw flat id -> swz; each XCD (flat%8) gets a contiguous
  // range of 192 swz ids = 6 (h,ks) slices of 32 q-tiles, ks varying fastest.
  const int flat = blockIdx.x + 32 * (blockIdx.y + 12 * blockIdx.z);
  const int swz = (flat & 7) * 192 + (flat >> 3);
  const int qt = swz & 31;
  const int rem = swz >> 5;        // 0..47
  const int ks = rem & 3;
  const int h = rem >> 2;          // 0..11

  const int tid = threadIdx.x;
  const int wave = tid >> 6, lane = tid & 63;
  const int quad = lane >> 4, l16 = lane & 15;
  const int q0 = qt * 128 + wave * 32;

  const bf16* Qh = Q + (size_t)h * S * DH;
  const bf16* kbase = Kf + (size_t)h * S * DH + (size_t)ks * (S / KSPLIT) * DH + lane * 8;
  const bf16* vbase = Vf + (size_t)h * S * DH + (size_t)ks * (S / KSPLIT) * DH + lane * 8;
  bf16* Op = ks == 0 ? Op0 : (ks == 1 ? Op1 : (ks == 2 ? Op2 : Op3));

  // Q fragments (B-operand): [qb][k-chunk]
  bf16x8 aq[2][2];
#pragma unroll
  for (int qb = 0; qb < 2; qb++)
#pragma unroll
    for (int j = 0; j < 2; j++)
      aq[qb][j] = *(const bf16x8*)&Qh[(size_t)(q0 + qb * 16 + l16) * DH + j * 32 + quad * 8];

  bf16x8 ones;
#pragma unroll
  for (int e = 0; e < 8; e++) ones[e] = (bf16)1.0f;

  f32x4 o[4][2] = {};   // [db][qb] : O^T accumulation (row=d, col=qrow)
  f32x4 ol[2] = {};     // row-sums L[qrow] via ones·P^T

  bf16* Pw = &P2[wave][0][0];

  const int T = (S / KSPLIT) / 64;  // 16
  for (int t = 0; t < T; ++t) {
    const bf16* kp = kbase + (size_t)t * 4096;
    bf16x8 kr[8];
#pragma unroll
    for (int i = 0; i < 8; i++) kr[i] = *(const bf16x8*)(kp + i * 512);

    // S^T = K·Q^T per (kb,qb); exp2; packed b64 store of 4 consecutive keys
#pragma unroll
    for (int kb = 0; kb < 4; kb++)
#pragma unroll
      for (int qb = 0; qb < 2; qb++) {
        f32x4 st = {};
        st = MFMA(kr[kb * 2], aq[qb][0], st);
        st = MFMA(kr[kb * 2 + 1], aq[qb][1], st);
        bf16x4 pk;
#pragma unroll
        for (int r = 0; r < 4; r++) pk[r] = (bf16)__builtin_exp2f(st[r]);
        *(bf16x4*)&Pw[(qb * 16 + l16) * 72 + kb * 16 + quad * 4] = pk;
      }

    // P^T B-fragments: 4 aligned ds_read_b128 (wave-internal lgkmcnt ordering)
    bf16x8 bp[2][2];
#pragma unroll
    for (int qb = 0; qb < 2; qb++)
#pragma unroll
      for (int jc = 0; jc < 2; jc++)
        bp[qb][jc] = *(const bf16x8*)&Pw[(qb * 16 + l16) * 72 + jc * 32 + quad * 8];

    // L[qrow] += ones · P^T  (MFMA pipe)
#pragma unroll
    for (int qb = 0; qb < 2; qb++) {
      ol[qb] = MFMA(ones, bp[qb][0], ol[qb]);
      ol[qb] = MFMA(ones, bp[qb][1], ol[qb]);
    }

    // O^T += V^T · P^T
    const bf16* vp = vbase + (size_t)t * 4096;
#pragma unroll
    for (int db = 0; db < 4; db++) {
      bf16x8 v0 = *(const bf16x8*)(vp + (db * 2) * 512);
      bf16x8 v1 = *(const bf16x8*)(vp + (db * 2 + 1) * 512);
#pragma unroll
      for (int qb = 0; qb < 2; qb++) {
        o[db][qb] = MFMA(v0, bp[qb][0], o[db][qb]);
        o[db][qb] = MFMA(v1, bp[qb][1], o[db][qb]);
      }
    }
  }

  // ---- epilogue ----
  // partial row-sums: ol[qb] C-layout col=l16=qrow (all rows identical)
  float* Lph = Lp + (size_t)(ks * NH + h) * S;
  if (quad == 0) {
#pragma unroll
    for (int qb = 0; qb < 2; qb++)
      Lph[q0 + qb * 16 + l16] = ol[qb][0];
  }
  // O^T -> LDS (reuse P2; per-wave region, wave-internal ordering)
#pragma unroll
  for (int db = 0; db < 4; db++)
#pragma unroll
    for (int qb = 0; qb < 2; qb++) {
      bf16x4 pk;
#pragma unroll
      for (int r = 0; r < 4; r++) pk[r] = (bf16)o[db][qb][r];
      *(bf16x4*)&Pw[(qb * 16 + l16) * 72 + db * 16 + quad * 4] = pk;
    }
  // coalesced stores: 8 rows/inst, 128B contiguous per row segment
  {
    const int rr = lane >> 3, ee = (lane & 7) * 8;
#pragma unroll
    for (int p = 0; p < 4; p++) {
      const int row = p * 8 + rr;
      bf16x8 c = *(const bf16x8*)&Pw[row * 72 + ee];
      *(bf16x8*)(Op + (size_t)(q0 + row) * E + h * DH + ee) = c;
    }
  }
}

// ---------------------------------------------------------------------------
// Combine ksplit partials: Obf = (Op0+Op1+Op2+Op3) / (L0+L1+L2+L3).
// Obf aliases Op0 (same-thread element-wise read-then-write — safe).
// ---------------------------------------------------------------------------
__global__ __launch_bounds__(256) void combine(const bf16* __restrict__ Op0,
                                               const bf16* __restrict__ Op1,
                                               const bf16* __restrict__ Op2,
                                               const bf16* __restrict__ Op3,
                                               const float* __restrict__ Lp,
                                               bf16* __restrict__ Obf) {
  const int i8 = blockIdx.x * 256 + threadIdx.x;
  const size_t base = (size_t)i8 * 8;
  const int row = (int)(base / E), c = (int)(base % E);
  const int h = c >> 6;
  const float l = Lp[(size_t)h * S + row] + Lp[(size_t)(NH + h) * S + row] +
                  Lp[(size_t)(2 * NH + h) * S + row] + Lp[(size_t)(3 * NH + h) * S + row];
  const float rl = 1.0f / l;
  bf16x8 a = *(const bf16x8*)(Op0 + base);
  bf16x8 b = *(const bf16x8*)(Op1 + base);
  bf16x8 cc = *(const bf16x8*)(Op2 + base);
  bf16x8 d = *(const bf16x8*)(Op3 + base);
  bf16x8 o;
#pragma unroll
  for (int e = 0; e < 8; e++)
    o[e] = (bf16)((((float)a[e] + (float)b[e]) + ((float)cc[e] + (float)d[e])) * rl);
  *(bf16x8*)(Obf + base) = o;
}

// ---------------------------------------------------------------------------
// Final projection: C[S][E] fp32 = A[S][E]bf16 @ WoT^T + b_o.
// 64x64 tile, BK=64 (k-halves stacked in LDS: one barrier pair per 64-K,
// halving barrier drains vs BK=32). grid (64,12) = 768 blocks = 3/CU.
// ---------------------------------------------------------------------------
__global__ __launch_bounds__(256) void gemm64(const bf16* __restrict__ A,
                                              const bf16* __restrict__ Bt,
                                              const float* __restrict__ bias,
                                              float* __restrict__ C) {
  __shared__ __align__(16) bf16 Asm[2][64 * 32];
  __shared__ __align__(16) bf16 Bsm[2][64 * 32];
  const int tid = threadIdx.x;
  const int wv = tid >> 6, lane = tid & 63;
  const int quad = lane >> 4, l16 = lane & 15;
  const int m0 = blockIdx.x * 64, n0 = blockIdx.y * 64;
  const int srow = lane >> 2, scol = (lane & 3) * 8;

  f32x4 acc[4] = {};

  for (int k0 = 0; k0 < E; k0 += 64) {
#pragma unroll
    for (int jc = 0; jc < 2; jc++) {
      async16(&A[(size_t)(m0 + wv * 16 + srow) * E + k0 + jc * 32 + scol], &Asm[jc][wv * 512]);
      async16(&Bt[(size_t)(n0 + wv * 16 + srow) * E + k0 + jc * 32 + scol], &Bsm[jc][wv * 512]);
    }
    __syncthreads();
#pragma unroll
    for (int jc = 0; jc < 2; jc++) {
      bf16x8 af = *(const bf16x8*)&Asm[jc][(wv * 16 + l16) * 32 + quad * 8];
#pragma unroll
      for (int ni = 0; ni < 4; ni++) {
        bf16x8 bfr = *(const bf16x8*)&Bsm[jc][(ni * 16 + l16) * 32 + quad * 8];
        acc[ni] = MFMA(af, bfr, acc[ni]);
      }
    }
    __syncthreads();
  }

  const int row0 = m0 + wv * 16 + quad * 4;
#pragma unroll
  for (int ni = 0; ni < 4; ni++) {
    const int col = n0 + ni * 16 + l16;
    const float bv = bias[col];
#pragma unroll
    for (int r = 0; r < 4; r++)
      C[(size_t)(row0 + r) * E + col] = acc[ni][r] + bv;
  }
}

// ---------------------------------------------------------------------------
// Launch
// ---------------------------------------------------------------------------
extern "C" void kernel_launch(void* const* d_in, const int* in_sizes, int n_in,
                              void* d_out, int out_size, void* d_ws, size_t ws_size,
                              hipStream_t stream) {
  (void)in_sizes; (void)n_in; (void)out_size; (void)ws_size;
  const float* q_in = (const float*)d_in[0];
  const float* k_in = (const float*)d_in[1];
  const float* v_in = (const float*)d_in[2];
  const float* W_q  = (const float*)d_in[3];
  const float* b_q  = (const float*)d_in[4];
  const float* W_k  = (const float*)d_in[5];
  const float* b_k  = (const float*)d_in[6];
  const float* W_v  = (const float*)d_in[7];
  const float* b_v  = (const float*)d_in[8];
  const float* W_o  = (const float*)d_in[9];
  const float* b_o  = (const float*)d_in[10];

  const size_t SE2 = (size_t)S * E * 2;   // bf16 [S][E] bytes
  const size_t EE2 = (size_t)E * E * 2;
  char* ws = (char*)d_ws;
  bf16* qb  = (bf16*)(ws);                    // dead after gemm128 -> Op1
  bf16* kb  = (bf16*)(ws + SE2);              // dead after gemm128 -> Op2
  bf16* vb  = (bf16*)(ws + 2 * SE2);          // dead after gemm128 -> Op3
  bf16* WqT = (bf16*)(ws + 3 * SE2);          // dead after gemm128 -> Lp
  bf16* WkT = (bf16*)(ws + 3 * SE2 + EE2);
  bf16* WvT = (bf16*)(ws + 3 * SE2 + 2 * EE2);
  bf16* WoT = (bf16*)(ws + 3 * SE2 + 3 * EE2);
  bf16* Qh  = (bf16*)(ws + 3 * SE2 + 4 * EE2);
  bf16* Kf  = (bf16*)(ws + 4 * SE2 + 4 * EE2);
  bf16* Vf  = (bf16*)(ws + 5 * SE2 + 4 * EE2);
  bf16* Obf = (bf16*)(ws + 6 * SE2 + 4 * EE2);  // also Op0
  bf16* Op1 = qb;
  bf16* Op2 = kb;
  bf16* Op3 = vb;
  float* Lp = (float*)WqT;                    // [4][NH][S] fp32 = 786 KB < EE2
  // total ws: 7*SE2 + 4*EE2 = 48,758,784 bytes

  prologue<<<dim3(2304 + 3 * 3072), 256, 0, stream>>>(
      q_in, k_in, v_in, W_q, W_k, W_v, W_o, qb, kb, vb, WqT, WkT, WvT, WoT);

  gemm128<<<dim3(S / 128, E / 128, 3), 256, 0, stream>>>(
      qb, kb, vb, WqT, WkT, WvT, b_q, b_k, b_v, Qh, Kf, Vf);

  attn<<<dim3(S / 128, NH, KSPLIT), 256, 0, stream>>>(Qh, Kf, Vf, Obf, Op1, Op2, Op3, Lp);

  combine<<<dim3(S * E / 2048), 256, 0, stream>>>(Obf, Op1, Op2, Op3, Lp, Obf);

  gemm64<<<dim3(S / 64, E / 64), 256, 0, stream>>>(Obf, WoT, b_o, (float*)d_out);
}

// Round 3
// 239.920 us; speedup vs baseline: 1.0389x; 1.0042x over previous
//
#include <hip/hip_runtime.h>

// Problem constants (reference: B=1, S=4096, D_EMB=768, H=12, D_QKV=64, INV_TEMP=1)
#define S 4096
#define E 768
#define NH 12
#define DH 64
// 1/sqrt(64) * log2(e): softmax computed in base 2 (exp2), scale folded into Q
#define QSCALE (0.125f * 1.44269504f)
#define KSPLIT 4

typedef __bf16 bf16;
typedef __bf16 bf16x4 __attribute__((ext_vector_type(4)));
typedef __bf16 bf16x8 __attribute__((ext_vector_type(8)));
typedef float  f32x4  __attribute__((ext_vector_type(4)));

#define MFMA(a, b, c) __builtin_amdgcn_mfma_f32_16x16x32_bf16(a, b, c, 0, 0, 0)

// async global->LDS, 16B per lane. Global address is PER-LANE; LDS dest is
// wave-uniform base (HW adds lane*16).
__device__ __forceinline__ void async16(const bf16* g, bf16* l) {
  __builtin_amdgcn_global_load_lds(
      (const __attribute__((address_space(1))) void*)g,
      (__attribute__((address_space(3))) void*)l, 16, 0, 0);
}

// ---------------------------------------------------------------------------
// Fused prologue: blocks 0..2303 transpose-cast the 4 weight matrices;
// blocks 2304.. cast q/k/v inputs to bf16.
// ---------------------------------------------------------------------------
__global__ __launch_bounds__(256) void prologue(const float* __restrict__ q_in,
                                                const float* __restrict__ k_in,
                                                const float* __restrict__ v_in,
                                                const float* __restrict__ w0,
                                                const float* __restrict__ w1,
                                                const float* __restrict__ w2,
                                                const float* __restrict__ w3,
                                                bf16* __restrict__ qb,
                                                bf16* __restrict__ kb,
                                                bf16* __restrict__ vb,
                                                bf16* __restrict__ t0,
                                                bf16* __restrict__ t1,
                                                bf16* __restrict__ t2,
                                                bf16* __restrict__ t3) {
  const int bid = blockIdx.x, tid = threadIdx.x;
  if (bid < 2304) {
    const int z = bid / 576, rem = bid % 576;
    const int bx = rem % 24, by = rem / 24;
    const float* W = z == 0 ? w0 : (z == 1 ? w1 : (z == 2 ? w2 : w3));
    bf16* Wt = z == 0 ? t0 : (z == 1 ? t1 : (z == 2 ? t2 : t3));
    __shared__ float t[32][33];
    const int tx = tid & 31, ty = tid >> 5;
    for (int j = ty; j < 32; j += 8)
      t[j][tx] = W[(by * 32 + j) * E + bx * 32 + tx];
    __syncthreads();
    for (int j = ty; j < 32; j += 8)
      Wt[(bx * 32 + j) * E + by * 32 + tx] = (bf16)t[tx][j];
  } else {
    const int b2 = bid - 2304;
    const int z = b2 / 3072, r2 = b2 % 3072;
    const float* in = z == 0 ? q_in : (z == 1 ? k_in : v_in);
    bf16* out = z == 0 ? qb : (z == 1 ? kb : vb);
    const int i = r2 * 1024 + tid * 4;
    float4 v = *(const float4*)(in + i);
    bf16x4 o = { (bf16)v.x, (bf16)v.y, (bf16)v.z, (bf16)v.w };
    *(bf16x4*)(out + i) = o;
  }
}

// ---------------------------------------------------------------------------
// QKV projection GEMM, 128x128 tile, batched over blockIdx.z (z=0 Q, 1 K, 2 V).
// async16 staging, BK=32, 4 waves 2x2, each 64x64. Epilogue stages C in LDS
// (stride 136; V transposed), then fully-coalesced writes:
//   z=0: Q*QSCALE -> [NH][S][DH] row-major
//   z=1: K -> fragment-linear: frag i of 64-key tile at tilebase+i*512+lane*8
//        i=nb*2+j holds K[t*64+nb*16+l16][j*32+quad*8+e]
//   z=2: V -> fragment-linear: i=db*2+jv holds V[t*64+jv*32+quad*8+e][db*16+l16]
// ---------------------------------------------------------------------------
__global__ __launch_bounds__(256) void gemm128(const bf16* __restrict__ A0,
                                               const bf16* __restrict__ A1,
                                               const bf16* __restrict__ A2,
                                               const bf16* __restrict__ B0,
                                               const bf16* __restrict__ B1,
                                               const bf16* __restrict__ B2,
                                               const float* __restrict__ bias0,
                                               const float* __restrict__ bias1,
                                               const float* __restrict__ bias2,
                                               bf16* __restrict__ C0,
                                               bf16* __restrict__ C1,
                                               bf16* __restrict__ C2) {
  __shared__ __align__(16) bf16 smem[128 * 136];
  bf16* Asm = smem;
  bf16* Bsm = smem + 4096;
  bf16* Cs  = smem;

  const int z = blockIdx.z;
  const bf16* A  = z == 0 ? A0 : (z == 1 ? A1 : A2);
  const bf16* Bt = z == 0 ? B0 : (z == 1 ? B1 : B2);
  const float* bias = z == 0 ? bias0 : (z == 1 ? bias1 : bias2);

  const int tid = threadIdx.x;
  const int wv = tid >> 6, lane = tid & 63;
  const int quad = lane >> 4, l16 = lane & 15;
  const int m0 = blockIdx.x * 128, n0 = blockIdx.y * 128;
  const int wm = (wv >> 1) * 64, wn = (wv & 1) * 64;
  const int srow = lane >> 2, scol = (lane & 3) * 8;

  f32x4 acc[4][4] = {};

  for (int k0 = 0; k0 < E; k0 += 32) {
#pragma unroll
    for (int j = 0; j < 2; j++) {
      const int ch = wv * 2 + j;  // wave-uniform
      async16(&A[(size_t)(m0 + ch * 16 + srow) * E + k0 + scol], &Asm[ch * 512]);
      async16(&Bt[(size_t)(n0 + ch * 16 + srow) * E + k0 + scol], &Bsm[ch * 512]);
    }
    __syncthreads();
    bf16x8 af[4], bfv[4];
#pragma unroll
    for (int mi = 0; mi < 4; mi++)
      af[mi] = *(const bf16x8*)&Asm[(wm + mi * 16 + l16) * 32 + quad * 8];
#pragma unroll
    for (int ni = 0; ni < 4; ni++)
      bfv[ni] = *(const bf16x8*)&Bsm[(wn + ni * 16 + l16) * 32 + quad * 8];
#pragma unroll
    for (int mi = 0; mi < 4; mi++)
#pragma unroll
      for (int ni = 0; ni < 4; ni++)
        acc[mi][ni] = MFMA(af[mi], bfv[ni], acc[mi][ni]);
    __syncthreads();
  }

  // ---- stage C tile into LDS ----
  const float scale = (z == 0) ? QSCALE : 1.0f;
#pragma unroll
  for (int mi = 0; mi < 4; mi++) {
#pragma unroll
    for (int ni = 0; ni < 4; ni++) {
      const int nl = wn + ni * 16 + l16;
      const float bv = bias[n0 + nl];
#pragma unroll
      for (int r = 0; r < 4; r++) {
        const int ml = wm + mi * 16 + quad * 4 + r;
        const float v = (acc[mi][ni][r] + bv) * scale;
        if (z == 2) Cs[nl * 136 + ml] = (bf16)v;   // V transposed [d][key]
        else        Cs[ml * 136 + nl] = (bf16)v;
      }
    }
  }
  __syncthreads();

  // ---- coalesced writeout ----
  if (z == 0) {
    const int e = lane & 7;
#pragma unroll
    for (int p = 0; p < 8; p++) {
      const int hr = p * 32 + wv * 8 + (lane >> 3);
      const int r = hr >> 1, hf = hr & 1;
      bf16x8 c = *(const bf16x8*)&Cs[r * 136 + hf * 64 + e * 8];
      *(bf16x8*)(C0 + (size_t)((n0 >> 6) + hf) * S * DH + (size_t)(m0 + r) * DH + e * 8) = c;
    }
  } else {
    bf16* dst = (z == 1) ? C1 : C2;
#pragma unroll
    for (int p = 0; p < 8; p++) {
      const int cid = p * 4 + wv;
      const int reg = cid >> 3;
      const int i = cid & 7;
      const int h_l = reg >> 1, tile = reg & 1;
      bf16x8 c;
      if (z == 1) {
        const int row = tile * 64 + (i >> 1) * 16 + l16;
        const int col = h_l * 64 + (i & 1) * 32 + quad * 8;
        c = *(const bf16x8*)&Cs[row * 136 + col];
      } else {
        const int nl = h_l * 64 + (i >> 1) * 16 + l16;
        const int ml = tile * 64 + (i & 1) * 32 + quad * 8;
        c = *(const bf16x8*)&Cs[nl * 136 + ml];
      }
      *(bf16x8*)(dst + (size_t)((n0 >> 6) + h_l) * S * DH +
                 (size_t)((m0 >> 6) + tile) * 4096 + i * 512 + lane * 8) = c;
    }
  }
}

// ---------------------------------------------------------------------------
// Flash attention, OPERAND-SWAPPED: S^T = K·Q^T, O^T = V^T·P^T.
// Round-3 structure: 64 q-rows/wave (round-0 geometry, best measured) +
//  (a) block-cooperative K/V staging: the 4 waves share each 16KB K/V tile
//      via LDS double-buffer (global traffic /4; was the largest pipe at
//      ~22us/CU). Staged with global_load_lds as a contiguous 8KB copy;
//      fragment-linear layout makes LDS reads identical to old global reads.
//  (b) counted-vmcnt prefetch pipeline: issue tile t+1's 4 loads, wait
//      vmcnt(4) (tile t landed, t+1 in flight), raw s_barrier — never a
//      full drain in the main loop (m97/m201 pattern).
//  (c) P scratch halved to [4][32][72] (two qb-pair half-passes per tile,
//      wave-internal ordering) so LDS = 16+16+18KB = 51,200B -> 3 blocks/CU
//      (grid 768 = exactly 3/CU, no occupancy loss).
//  (d) XCD swizzle kept from round-2 (proven: FETCH 55->10MB): each XCD owns
//      96 consecutive blocks = 6 (h,ks) slices -> ~3MB working set < 4MB L2.
// Round-1 lesson kept: P redistribution stays as LDS round-trip (permlane
// variant put VALU on the critical path and regressed).
// ---------------------------------------------------------------------------
__global__ __launch_bounds__(256, 3) void attn(const bf16* __restrict__ Q,
                                               const bf16* __restrict__ Kf,
                                               const bf16* __restrict__ Vf,
                                               bf16* __restrict__ Op0,
                                               bf16* __restrict__ Op1,
                                               bf16* __restrict__ Op2,
                                               bf16* __restrict__ Op3,
                                               float* __restrict__ Lp) {
  __shared__ __align__(16) bf16 Kbuf[2][4096];   // 16,384 B
  __shared__ __align__(16) bf16 Vbuf[2][4096];   // 16,384 B
  __shared__ __align__(16) bf16 P2[4][32][72];   // 18,432 B; total 51,200 B

  // XCD-aware remap: 768 blocks, 96 contiguous per XCD (q-tile fastest).
  const int flat = blockIdx.x + 16 * (blockIdx.y + 12 * blockIdx.z);
  const int swz = (flat & 7) * 96 + (flat >> 3);
  const int qt = swz & 15;
  const int rem = swz >> 4;        // 0..47
  const int ks = rem & 3;
  const int h = rem >> 2;          // 0..11

  const int tid = threadIdx.x;
  const int wave = tid >> 6, lane = tid & 63;
  const int quad = lane >> 4, l16 = lane & 15;
  const int q0 = qt * 256 + wave * 64;

  const bf16* Qh = Q + (size_t)h * S * DH;
  const bf16* kbase = Kf + (size_t)h * S * DH + (size_t)ks * (S / KSPLIT) * DH;
  const bf16* vbase = Vf + (size_t)h * S * DH + (size_t)ks * (S / KSPLIT) * DH;
  bf16* Op = ks == 0 ? Op0 : (ks == 1 ? Op1 : (ks == 2 ? Op2 : Op3));

  // Stage one 64-key tile (8KB K + 8KB V) cooperatively: wave w copies its
  // 2KB chunk of each. 4 vmem ops per wave per tile.
  auto stageKV = [&](int buf, int t) {
    const bf16* kg = kbase + (size_t)t * 4096 + wave * 1024 + lane * 8;
    const bf16* vg = vbase + (size_t)t * 4096 + wave * 1024 + lane * 8;
    async16(kg,       &Kbuf[buf][wave * 1024]);
    async16(kg + 512, &Kbuf[buf][wave * 1024 + 512]);
    async16(vg,       &Vbuf[buf][wave * 1024]);
    async16(vg + 512, &Vbuf[buf][wave * 1024 + 512]);
  };

  stageKV(0, 0);  // prologue: tile 0 in flight ASAP

  // Q fragments (B-operand): [qb][k-chunk]
  bf16x8 aq[4][2];
#pragma unroll
  for (int qb = 0; qb < 4; qb++)
#pragma unroll
    for (int j = 0; j < 2; j++)
      aq[qb][j] = *(const bf16x8*)&Qh[(size_t)(q0 + qb * 16 + l16) * DH + j * 32 + quad * 8];

  bf16x8 ones;
#pragma unroll
  for (int e = 0; e < 8; e++) ones[e] = (bf16)1.0f;

  f32x4 o[4][4] = {};   // [db][qb] : O^T accumulation (row=d, col=qrow)
  f32x4 ol[4] = {};     // row-sums L[qrow] via ones·P^T

  bf16* Pw = &P2[wave][0][0];

  const int T = (S / KSPLIT) / 64;  // 16
  for (int t = 0; t < T; ++t) {
    if (t + 1 < T) {
      stageKV((t + 1) & 1, t + 1);
      // tile t's 4 loads complete; tile t+1's 4 stay in flight
      asm volatile("s_waitcnt vmcnt(4)" ::: "memory");
    } else {
      asm volatile("s_waitcnt vmcnt(0)" ::: "memory");
    }
    asm volatile("s_barrier" ::: "memory");   // all waves' stage of buf[t&1] visible

    const bf16* kp = &Kbuf[t & 1][lane * 8];
    const bf16* vp = &Vbuf[t & 1][lane * 8];
    bf16x8 kr[8];
#pragma unroll
    for (int i = 0; i < 8; i++) kr[i] = *(const bf16x8*)(kp + i * 512);

#pragma unroll
    for (int half = 0; half < 2; half++) {
      // S^T = K·Q^T for this qb-pair; exp2; packed b64 store of 4 keys
#pragma unroll
      for (int kb = 0; kb < 4; kb++)
#pragma unroll
        for (int q2 = 0; q2 < 2; q2++) {
          const int qb = half * 2 + q2;
          f32x4 st = {};
          st = MFMA(kr[kb * 2], aq[qb][0], st);
          st = MFMA(kr[kb * 2 + 1], aq[qb][1], st);
          bf16x4 pk;
#pragma unroll
          for (int r = 0; r < 4; r++) pk[r] = (bf16)__builtin_exp2f(st[r]);
          *(bf16x4*)&Pw[(q2 * 16 + l16) * 72 + kb * 16 + quad * 4] = pk;
        }

      // P^T B-fragments: 4 aligned ds_read_b128 (wave-internal ordering)
      bf16x8 bp[2][2];
#pragma unroll
      for (int q2 = 0; q2 < 2; q2++)
#pragma unroll
        for (int jc = 0; jc < 2; jc++)
          bp[q2][jc] = *(const bf16x8*)&Pw[(q2 * 16 + l16) * 72 + jc * 32 + quad * 8];

      // L[qrow] += ones · P^T  (MFMA pipe)
#pragma unroll
      for (int q2 = 0; q2 < 2; q2++) {
        ol[half * 2 + q2] = MFMA(ones, bp[q2][0], ol[half * 2 + q2]);
        ol[half * 2 + q2] = MFMA(ones, bp[q2][1], ol[half * 2 + q2]);
      }

      // O^T += V^T · P^T  (V fragments from LDS)
#pragma unroll
      for (int db = 0; db < 4; db++) {
        bf16x8 v0 = *(const bf16x8*)(vp + (db * 2) * 512);
        bf16x8 v1 = *(const bf16x8*)(vp + (db * 2 + 1) * 512);
#pragma unroll
        for (int q2 = 0; q2 < 2; q2++) {
          o[db][half * 2 + q2] = MFMA(v0, bp[q2][0], o[db][half * 2 + q2]);
          o[db][half * 2 + q2] = MFMA(v1, bp[q2][1], o[db][half * 2 + q2]);
        }
      }
    }

    // readers done with buf[t&1] before iter t+1 re-stages it
    asm volatile("s_barrier" ::: "memory");
  }

  // ---- epilogue ----
  // partial row-sums: ol[qb] C-layout col=l16=qrow (all rows identical)
  float* Lph = Lp + (size_t)(ks * NH + h) * S;
  if (quad == 0) {
#pragma unroll
    for (int qb = 0; qb < 4; qb++)
      Lph[q0 + qb * 16 + l16] = ol[qb][0];
  }
  // O^T -> LDS (reuse P2 per-wave region) in two 32-row halves; coalesced out
#pragma unroll
  for (int half = 0; half < 2; half++) {
#pragma unroll
    for (int db = 0; db < 4; db++)
#pragma unroll
      for (int q2 = 0; q2 < 2; q2++) {
        bf16x4 pk;
#pragma unroll
        for (int r = 0; r < 4; r++) pk[r] = (bf16)o[db][half * 2 + q2][r];
        *(bf16x4*)&Pw[(q2 * 16 + l16) * 72 + db * 16 + quad * 4] = pk;
      }
    const int rr = lane >> 3, ee = (lane & 7) * 8;
#pragma unroll
    for (int p = 0; p < 4; p++) {
      const int row = p * 8 + rr;
      bf16x8 c = *(const bf16x8*)&Pw[row * 72 + ee];
      *(bf16x8*)(Op + (size_t)(q0 + half * 32 + row) * E + h * DH + ee) = c;
    }
  }
}

// ---------------------------------------------------------------------------
// Combine ksplit partials: Obf = (Op0+Op1+Op2+Op3) / (L0+L1+L2+L3).
// Obf aliases Op0 (same-thread element-wise read-then-write — safe).
// ---------------------------------------------------------------------------
__global__ __launch_bounds__(256) void combine(const bf16* __restrict__ Op0,
                                               const bf16* __restrict__ Op1,
                                               const bf16* __restrict__ Op2,
                                               const bf16* __restrict__ Op3,
                                               const float* __restrict__ Lp,
                                               bf16* __restrict__ Obf) {
  const int i8 = blockIdx.x * 256 + threadIdx.x;
  const size_t base = (size_t)i8 * 8;
  const int row = (int)(base / E), c = (int)(base % E);
  const int h = c >> 6;
  const float l = Lp[(size_t)h * S + row] + Lp[(size_t)(NH + h) * S + row] +
                  Lp[(size_t)(2 * NH + h) * S + row] + Lp[(size_t)(3 * NH + h) * S + row];
  const float rl = 1.0f / l;
  bf16x8 a = *(const bf16x8*)(Op0 + base);
  bf16x8 b = *(const bf16x8*)(Op1 + base);
  bf16x8 cc = *(const bf16x8*)(Op2 + base);
  bf16x8 d = *(const bf16x8*)(Op3 + base);
  bf16x8 o;
#pragma unroll
  for (int e = 0; e < 8; e++)
    o[e] = (bf16)((((float)a[e] + (float)b[e]) + ((float)cc[e] + (float)d[e])) * rl);
  *(bf16x8*)(Obf + base) = o;
}

// ---------------------------------------------------------------------------
// Final projection: C[S][E] fp32 = A[S][E]bf16 @ WoT^T + b_o.
// 64x64 tile, BK=64 (k-halves stacked in LDS: one barrier pair per 64-K,
// halving barrier drains vs BK=32). grid (64,12) = 768 blocks = 3/CU.
// ---------------------------------------------------------------------------
__global__ __launch_bounds__(256) void gemm64(const bf16* __restrict__ A,
                                              const bf16* __restrict__ Bt,
                                              const float* __restrict__ bias,
                                              float* __restrict__ C) {
  __shared__ __align__(16) bf16 Asm[2][64 * 32];
  __shared__ __align__(16) bf16 Bsm[2][64 * 32];
  const int tid = threadIdx.x;
  const int wv = tid >> 6, lane = tid & 63;
  const int quad = lane >> 4, l16 = lane & 15;
  const int m0 = blockIdx.x * 64, n0 = blockIdx.y * 64;
  const int srow = lane >> 2, scol = (lane & 3) * 8;

  f32x4 acc[4] = {};

  for (int k0 = 0; k0 < E; k0 += 64) {
#pragma unroll
    for (int jc = 0; jc < 2; jc++) {
      async16(&A[(size_t)(m0 + wv * 16 + srow) * E + k0 + jc * 32 + scol], &Asm[jc][wv * 512]);
      async16(&Bt[(size_t)(n0 + wv * 16 + srow) * E + k0 + jc * 32 + scol], &Bsm[jc][wv * 512]);
    }
    __syncthreads();
#pragma unroll
    for (int jc = 0; jc < 2; jc++) {
      bf16x8 af = *(const bf16x8*)&Asm[jc][(wv * 16 + l16) * 32 + quad * 8];
#pragma unroll
      for (int ni = 0; ni < 4; ni++) {
        bf16x8 bfr = *(const bf16x8*)&Bsm[jc][(ni * 16 + l16) * 32 + quad * 8];
        acc[ni] = MFMA(af, bfr, acc[ni]);
      }
    }
    __syncthreads();
  }

  const int row0 = m0 + wv * 16 + quad * 4;
#pragma unroll
  for (int ni = 0; ni < 4; ni++) {
    const int col = n0 + ni * 16 + l16;
    const float bv = bias[col];
#pragma unroll
    for (int r = 0; r < 4; r++)
      C[(size_t)(row0 + r) * E + col] = acc[ni][r] + bv;
  }
}

// ---------------------------------------------------------------------------
// Launch
// ---------------------------------------------------------------------------
extern "C" void kernel_launch(void* const* d_in, const int* in_sizes, int n_in,
                              void* d_out, int out_size, void* d_ws, size_t ws_size,
                              hipStream_t stream) {
  (void)in_sizes; (void)n_in; (void)out_size; (void)ws_size;
  const float* q_in = (const float*)d_in[0];
  const float* k_in = (const float*)d_in[1];
  const float* v_in = (const float*)d_in[2];
  const float* W_q  = (const float*)d_in[3];
  const float* b_q  = (const float*)d_in[4];
  const float* W_k  = (const float*)d_in[5];
  const float* b_k  = (const float*)d_in[6];
  const float* W_v  = (const float*)d_in[7];
  const float* b_v  = (const float*)d_in[8];
  const float* W_o  = (const float*)d_in[9];
  const float* b_o  = (const float*)d_in[10];

  const size_t SE2 = (size_t)S * E * 2;   // bf16 [S][E] bytes
  const size_t EE2 = (size_t)E * E * 2;
  char* ws = (char*)d_ws;
  bf16* qb  = (bf16*)(ws);                    // dead after gemm128 -> Op1
  bf16* kb  = (bf16*)(ws + SE2);              // dead after gemm128 -> Op2
  bf16* vb  = (bf16*)(ws + 2 * SE2);          // dead after gemm128 -> Op3
  bf16* WqT = (bf16*)(ws + 3 * SE2);          // dead after gemm128 -> Lp
  bf16* WkT = (bf16*)(ws + 3 * SE2 + EE2);
  bf16* WvT = (bf16*)(ws + 3 * SE2 + 2 * EE2);
  bf16* WoT = (bf16*)(ws + 3 * SE2 + 3 * EE2);
  bf16* Qh  = (bf16*)(ws + 3 * SE2 + 4 * EE2);
  bf16* Kf  = (bf16*)(ws + 4 * SE2 + 4 * EE2);
  bf16* Vf  = (bf16*)(ws + 5 * SE2 + 4 * EE2);
  bf16* Obf = (bf16*)(ws + 6 * SE2 + 4 * EE2);  // also Op0
  bf16* Op1 = qb;
  bf16* Op2 = kb;
  bf16* Op3 = vb;
  float* Lp = (float*)WqT;                    // [4][NH][S] fp32 = 786 KB < EE2
  // total ws: 7*SE2 + 4*EE2 = 48,758,784 bytes

  prologue<<<dim3(2304 + 3 * 3072), 256, 0, stream>>>(
      q_in, k_in, v_in, W_q, W_k, W_v, W_o, qb, kb, vb, WqT, WkT, WvT, WoT);

  gemm128<<<dim3(S / 128, E / 128, 3), 256, 0, stream>>>(
      qb, kb, vb, WqT, WkT, WvT, b_q, b_k, b_v, Qh, Kf, Vf);

  attn<<<dim3(S / 256, NH, KSPLIT), 256, 0, stream>>>(Qh, Kf, Vf, Obf, Op1, Op2, Op3, Lp);

  combine<<<dim3(S * E / 2048), 256, 0, stream>>>(Obf, Op1, Op2, Op3, Lp, Obf);

  gemm64<<<dim3(S / 64, E / 64), 256, 0, stream>>>(Obf, WoT, b_o, (float*)d_out);
}

// Round 4
// 226.513 us; speedup vs baseline: 1.1004x; 1.0592x over previous
//
#include <hip/hip_runtime.h>

// Problem constants (reference: B=1, S=4096, D_EMB=768, H=12, D_QKV=64, INV_TEMP=1)
#define S 4096
#define E 768
#define NH 12
#define DH 64
// 1/sqrt(64) * log2(e): softmax computed in base 2 (exp2), scale folded into Q
#define QSCALE (0.125f * 1.44269504f)
#define KSPLIT 4

typedef __bf16 bf16;
typedef __bf16 bf16x4 __attribute__((ext_vector_type(4)));
typedef __bf16 bf16x8 __attribute__((ext_vector_type(8)));
typedef float  f32x4  __attribute__((ext_vector_type(4)));

#define MFMA(a, b, c) __builtin_amdgcn_mfma_f32_16x16x32_bf16(a, b, c, 0, 0, 0)

// async global->LDS, 16B per lane. Global address is PER-LANE; LDS dest is
// wave-uniform base (HW adds lane*16).
__device__ __forceinline__ void async16(const bf16* g, bf16* l) {
  __builtin_amdgcn_global_load_lds(
      (const __attribute__((address_space(1))) void*)g,
      (__attribute__((address_space(3))) void*)l, 16, 0, 0);
}

// ---------------------------------------------------------------------------
// Fused prologue: blocks 0..2303 transpose-cast the 4 weight matrices;
// blocks 2304.. cast q/k/v inputs to bf16.
// ---------------------------------------------------------------------------
__global__ __launch_bounds__(256) void prologue(const float* __restrict__ q_in,
                                                const float* __restrict__ k_in,
                                                const float* __restrict__ v_in,
                                                const float* __restrict__ w0,
                                                const float* __restrict__ w1,
                                                const float* __restrict__ w2,
                                                const float* __restrict__ w3,
                                                bf16* __restrict__ qb,
                                                bf16* __restrict__ kb,
                                                bf16* __restrict__ vb,
                                                bf16* __restrict__ t0,
                                                bf16* __restrict__ t1,
                                                bf16* __restrict__ t2,
                                                bf16* __restrict__ t3) {
  const int bid = blockIdx.x, tid = threadIdx.x;
  if (bid < 2304) {
    const int z = bid / 576, rem = bid % 576;
    const int bx = rem % 24, by = rem / 24;
    const float* W = z == 0 ? w0 : (z == 1 ? w1 : (z == 2 ? w2 : w3));
    bf16* Wt = z == 0 ? t0 : (z == 1 ? t1 : (z == 2 ? t2 : t3));
    __shared__ float t[32][33];
    const int tx = tid & 31, ty = tid >> 5;
    for (int j = ty; j < 32; j += 8)
      t[j][tx] = W[(by * 32 + j) * E + bx * 32 + tx];
    __syncthreads();
    for (int j = ty; j < 32; j += 8)
      Wt[(bx * 32 + j) * E + by * 32 + tx] = (bf16)t[tx][j];
  } else {
    const int b2 = bid - 2304;
    const int z = b2 / 3072, r2 = b2 % 3072;
    const float* in = z == 0 ? q_in : (z == 1 ? k_in : v_in);
    bf16* out = z == 0 ? qb : (z == 1 ? kb : vb);
    const int i = r2 * 1024 + tid * 4;
    float4 v = *(const float4*)(in + i);
    bf16x4 o = { (bf16)v.x, (bf16)v.y, (bf16)v.z, (bf16)v.w };
    *(bf16x4*)(out + i) = o;
  }
}

// ---------------------------------------------------------------------------
// QKV projection GEMM, 128x128 tile, batched over blockIdx.z (z=0 Q, 1 K, 2 V).
// async16 staging, BK=32, 4 waves 2x2, each 64x64. Epilogue stages C in LDS
// (stride 136; V transposed), then fully-coalesced writes:
//   z=0: Q*QSCALE -> [NH][S][DH] row-major
//   z=1: K -> fragment-linear: frag i of 64-key tile at tilebase+i*512+lane*8
//        i=nb*2+j holds K[t*64+nb*16+l16][j*32+quad*8+e]
//   z=2: V -> fragment-linear: i=db*2+jv holds V[t*64+jv*32+quad*8+e][db*16+l16]
// ---------------------------------------------------------------------------
__global__ __launch_bounds__(256) void gemm128(const bf16* __restrict__ A0,
                                               const bf16* __restrict__ A1,
                                               const bf16* __restrict__ A2,
                                               const bf16* __restrict__ B0,
                                               const bf16* __restrict__ B1,
                                               const bf16* __restrict__ B2,
                                               const float* __restrict__ bias0,
                                               const float* __restrict__ bias1,
                                               const float* __restrict__ bias2,
                                               bf16* __restrict__ C0,
                                               bf16* __restrict__ C1,
                                               bf16* __restrict__ C2) {
  __shared__ __align__(16) bf16 smem[128 * 136];
  bf16* Asm = smem;
  bf16* Bsm = smem + 4096;
  bf16* Cs  = smem;

  const int z = blockIdx.z;
  const bf16* A  = z == 0 ? A0 : (z == 1 ? A1 : A2);
  const bf16* Bt = z == 0 ? B0 : (z == 1 ? B1 : B2);
  const float* bias = z == 0 ? bias0 : (z == 1 ? bias1 : bias2);

  const int tid = threadIdx.x;
  const int wv = tid >> 6, lane = tid & 63;
  const int quad = lane >> 4, l16 = lane & 15;
  const int m0 = blockIdx.x * 128, n0 = blockIdx.y * 128;
  const int wm = (wv >> 1) * 64, wn = (wv & 1) * 64;
  const int srow = lane >> 2, scol = (lane & 3) * 8;

  f32x4 acc[4][4] = {};

  for (int k0 = 0; k0 < E; k0 += 32) {
#pragma unroll
    for (int j = 0; j < 2; j++) {
      const int ch = wv * 2 + j;  // wave-uniform
      async16(&A[(size_t)(m0 + ch * 16 + srow) * E + k0 + scol], &Asm[ch * 512]);
      async16(&Bt[(size_t)(n0 + ch * 16 + srow) * E + k0 + scol], &Bsm[ch * 512]);
    }
    __syncthreads();
    bf16x8 af[4], bfv[4];
#pragma unroll
    for (int mi = 0; mi < 4; mi++)
      af[mi] = *(const bf16x8*)&Asm[(wm + mi * 16 + l16) * 32 + quad * 8];
#pragma unroll
    for (int ni = 0; ni < 4; ni++)
      bfv[ni] = *(const bf16x8*)&Bsm[(wn + ni * 16 + l16) * 32 + quad * 8];
#pragma unroll
    for (int mi = 0; mi < 4; mi++)
#pragma unroll
      for (int ni = 0; ni < 4; ni++)
        acc[mi][ni] = MFMA(af[mi], bfv[ni], acc[mi][ni]);
    __syncthreads();
  }

  // ---- stage C tile into LDS ----
  const float scale = (z == 0) ? QSCALE : 1.0f;
#pragma unroll
  for (int mi = 0; mi < 4; mi++) {
#pragma unroll
    for (int ni = 0; ni < 4; ni++) {
      const int nl = wn + ni * 16 + l16;
      const float bv = bias[n0 + nl];
#pragma unroll
      for (int r = 0; r < 4; r++) {
        const int ml = wm + mi * 16 + quad * 4 + r;
        const float v = (acc[mi][ni][r] + bv) * scale;
        if (z == 2) Cs[nl * 136 + ml] = (bf16)v;   // V transposed [d][key]
        else        Cs[ml * 136 + nl] = (bf16)v;
      }
    }
  }
  __syncthreads();

  // ---- coalesced writeout ----
  if (z == 0) {
    const int e = lane & 7;
#pragma unroll
    for (int p = 0; p < 8; p++) {
      const int hr = p * 32 + wv * 8 + (lane >> 3);
      const int r = hr >> 1, hf = hr & 1;
      bf16x8 c = *(const bf16x8*)&Cs[r * 136 + hf * 64 + e * 8];
      *(bf16x8*)(C0 + (size_t)((n0 >> 6) + hf) * S * DH + (size_t)(m0 + r) * DH + e * 8) = c;
    }
  } else {
    bf16* dst = (z == 1) ? C1 : C2;
#pragma unroll
    for (int p = 0; p < 8; p++) {
      const int cid = p * 4 + wv;
      const int reg = cid >> 3;
      const int i = cid & 7;
      const int h_l = reg >> 1, tile = reg & 1;
      bf16x8 c;
      if (z == 1) {
        const int row = tile * 64 + (i >> 1) * 16 + l16;
        const int col = h_l * 64 + (i & 1) * 32 + quad * 8;
        c = *(const bf16x8*)&Cs[row * 136 + col];
      } else {
        const int nl = h_l * 64 + (i >> 1) * 16 + l16;
        const int ml = tile * 64 + (i & 1) * 32 + quad * 8;
        c = *(const bf16x8*)&Cs[nl * 136 + ml];
      }
      *(bf16x8*)(dst + (size_t)((n0 >> 6) + h_l) * S * DH +
                 (size_t)((m0 >> 6) + tile) * 4096 + i * 512 + lane * 8) = c;
    }
  }
}

// ---------------------------------------------------------------------------
// Flash attention, OPERAND-SWAPPED: S^T = K·Q^T, O^T = V^T·P^T.
// Round-4: EXACT round-0 structure (95.6us best: wave-independent main loop,
// no barriers, LDS P round-trip — self-staggering waves) + ONE change:
// XCD-aware block swizzle. Each XCD owns 96 consecutive blocks = 6 (h,ks)
// slices x 16 q-tiles; per-XCD hot K/V = 6 x 256KB = 1.5MB < 4MB L2, so the
// 16 blocks sharing a slice hit their own XCD's L2 (round-3 measured this
// decode: FETCH 55 -> 19MB). Rationale: kernel is latency-bound (all pipes
// 20-25%); converting ~900cy HBM misses into ~200cy L2 hits shortens the
// per-tile dependency chain.
// History: r1 permlane redistribution = regression (VALU critical path);
// r2 32-row waves = regression (halved arithmetic intensity); r3 block-coop
// staging = regression (barrier lockstep, write amplification).
// ---------------------------------------------------------------------------
__global__ __launch_bounds__(256, 3) void attn(const bf16* __restrict__ Q,
                                               const bf16* __restrict__ Kf,
                                               const bf16* __restrict__ Vf,
                                               bf16* __restrict__ Op0,
                                               bf16* __restrict__ Op1,
                                               bf16* __restrict__ Op2,
                                               bf16* __restrict__ Op3,
                                               float* __restrict__ Lp) {
  __shared__ __align__(16) bf16 P2[4][64][72];   // per-wave P[qrow][key]; 36,864 B
  // XCD-aware remap: 768 blocks; hw dispatch round-robins flat%8 across XCDs.
  // swz = (flat%8)*96 + flat/8 gives each XCD a contiguous swz range.
  const int flat = blockIdx.x + 16 * (blockIdx.y + 12 * blockIdx.z);
  const int swz = (flat & 7) * 96 + (flat >> 3);
  const int qt = swz & 15;         // q-tile (fastest within an XCD's range)
  const int rem = swz >> 4;        // 0..47
  const int ks = rem & 3;
  const int h = rem >> 2;          // 0..11

  const int tid = threadIdx.x;
  const int wave = tid >> 6, lane = tid & 63;
  const int quad = lane >> 4, l16 = lane & 15;
  const int q0 = qt * 256 + wave * 64;

  const bf16* Qh = Q + (size_t)h * S * DH;
  const bf16* kbase = Kf + (size_t)h * S * DH + (size_t)ks * (S / KSPLIT) * DH + lane * 8;
  const bf16* vbase = Vf + (size_t)h * S * DH + (size_t)ks * (S / KSPLIT) * DH + lane * 8;
  bf16* Op = ks == 0 ? Op0 : (ks == 1 ? Op1 : (ks == 2 ? Op2 : Op3));

  // Q fragments (B-operand): [qb][k-chunk]
  bf16x8 aq[4][2];
#pragma unroll
  for (int qb = 0; qb < 4; qb++)
#pragma unroll
    for (int j = 0; j < 2; j++)
      aq[qb][j] = *(const bf16x8*)&Qh[(size_t)(q0 + qb * 16 + l16) * DH + j * 32 + quad * 8];

  bf16x8 ones;
#pragma unroll
  for (int e = 0; e < 8; e++) ones[e] = (bf16)1.0f;

  f32x4 o[4][4] = {};   // [db][qb] : O^T accumulation (row=d, col=qrow)
  f32x4 ol[4] = {};     // row-sums L[qrow] via ones·P^T

  bf16* Pw = &P2[wave][0][0];

  const int T = (S / KSPLIT) / 64;  // 16
  for (int t = 0; t < T; ++t) {
    const bf16* kp = kbase + (size_t)t * 4096;
    bf16x8 kr[8];
#pragma unroll
    for (int i = 0; i < 8; i++) kr[i] = *(const bf16x8*)(kp + i * 512);

    // S^T = K·Q^T per (kb,qb); exp2; packed b64 store of 4 consecutive keys
#pragma unroll
    for (int kb = 0; kb < 4; kb++)
#pragma unroll
      for (int qb = 0; qb < 4; qb++) {
        f32x4 st = {};
        st = MFMA(kr[kb * 2], aq[qb][0], st);
        st = MFMA(kr[kb * 2 + 1], aq[qb][1], st);
        bf16x4 pk;
#pragma unroll
        for (int r = 0; r < 4; r++) pk[r] = (bf16)__builtin_exp2f(st[r]);
        *(bf16x4*)&Pw[(qb * 16 + l16) * 72 + kb * 16 + quad * 4] = pk;
      }

    // P^T B-fragments: 8 aligned ds_read_b128 (wave-internal lgkmcnt ordering)
    bf16x8 bp[4][2];
#pragma unroll
    for (int qb = 0; qb < 4; qb++)
#pragma unroll
      for (int jc = 0; jc < 2; jc++)
        bp[qb][jc] = *(const bf16x8*)&Pw[(qb * 16 + l16) * 72 + jc * 32 + quad * 8];

    // L[qrow] += ones · P^T  (MFMA pipe)
#pragma unroll
    for (int qb = 0; qb < 4; qb++) {
      ol[qb] = MFMA(ones, bp[qb][0], ol[qb]);
      ol[qb] = MFMA(ones, bp[qb][1], ol[qb]);
    }

    // O^T += V^T · P^T
    const bf16* vp = vbase + (size_t)t * 4096;
#pragma unroll
    for (int db = 0; db < 4; db++) {
      bf16x8 v0 = *(const bf16x8*)(vp + (db * 2) * 512);
      bf16x8 v1 = *(const bf16x8*)(vp + (db * 2 + 1) * 512);
#pragma unroll
      for (int qb = 0; qb < 4; qb++) {
        o[db][qb] = MFMA(v0, bp[qb][0], o[db][qb]);
        o[db][qb] = MFMA(v1, bp[qb][1], o[db][qb]);
      }
    }
  }

  // ---- epilogue ----
  // partial row-sums: ol[qb] C-layout col=l16=qrow (all rows identical)
  float* Lph = Lp + (size_t)(ks * NH + h) * S;
  if (quad == 0) {
#pragma unroll
    for (int qb = 0; qb < 4; qb++)
      Lph[q0 + qb * 16 + l16] = ol[qb][0];
  }
  // O^T -> LDS (reuse P2; per-wave region, wave-internal ordering)
#pragma unroll
  for (int db = 0; db < 4; db++)
#pragma unroll
    for (int qb = 0; qb < 4; qb++) {
      bf16x4 pk;
#pragma unroll
      for (int r = 0; r < 4; r++) pk[r] = (bf16)o[db][qb][r];
      *(bf16x4*)&Pw[(qb * 16 + l16) * 72 + db * 16 + quad * 4] = pk;
    }
  // coalesced stores: 8 rows/inst, 128B contiguous per row segment
  {
    const int rr = lane >> 3, ee = (lane & 7) * 8;
#pragma unroll
    for (int p = 0; p < 8; p++) {
      const int row = p * 8 + rr;
      bf16x8 c = *(const bf16x8*)&Pw[row * 72 + ee];
      *(bf16x8*)(Op + (size_t)(q0 + row) * E + h * DH + ee) = c;
    }
  }
}

// ---------------------------------------------------------------------------
// Combine ksplit partials: Obf = (Op0+Op1+Op2+Op3) / (L0+L1+L2+L3).
// Obf aliases Op0 (same-thread element-wise read-then-write — safe).
// ---------------------------------------------------------------------------
__global__ __launch_bounds__(256) void combine(const bf16* __restrict__ Op0,
                                               const bf16* __restrict__ Op1,
                                               const bf16* __restrict__ Op2,
                                               const bf16* __restrict__ Op3,
                                               const float* __restrict__ Lp,
                                               bf16* __restrict__ Obf) {
  const int i8 = blockIdx.x * 256 + threadIdx.x;
  const size_t base = (size_t)i8 * 8;
  const int row = (int)(base / E), c = (int)(base % E);
  const int h = c >> 6;
  const float l = Lp[(size_t)h * S + row] + Lp[(size_t)(NH + h) * S + row] +
                  Lp[(size_t)(2 * NH + h) * S + row] + Lp[(size_t)(3 * NH + h) * S + row];
  const float rl = 1.0f / l;
  bf16x8 a = *(const bf16x8*)(Op0 + base);
  bf16x8 b = *(const bf16x8*)(Op1 + base);
  bf16x8 cc = *(const bf16x8*)(Op2 + base);
  bf16x8 d = *(const bf16x8*)(Op3 + base);
  bf16x8 o;
#pragma unroll
  for (int e = 0; e < 8; e++)
    o[e] = (bf16)((((float)a[e] + (float)b[e]) + ((float)cc[e] + (float)d[e])) * rl);
  *(bf16x8*)(Obf + base) = o;
}

// ---------------------------------------------------------------------------
// Final projection: C[S][E] fp32 = A[S][E]bf16 @ WoT^T + b_o.
// 64x64 tile, BK=64 (k-halves stacked in LDS: one barrier pair per 64-K,
// halving barrier drains vs BK=32). grid (64,12) = 768 blocks = 3/CU.
// ---------------------------------------------------------------------------
__global__ __launch_bounds__(256) void gemm64(const bf16* __restrict__ A,
                                              const bf16* __restrict__ Bt,
                                              const float* __restrict__ bias,
                                              float* __restrict__ C) {
  __shared__ __align__(16) bf16 Asm[2][64 * 32];
  __shared__ __align__(16) bf16 Bsm[2][64 * 32];
  const int tid = threadIdx.x;
  const int wv = tid >> 6, lane = tid & 63;
  const int quad = lane >> 4, l16 = lane & 15;
  const int m0 = blockIdx.x * 64, n0 = blockIdx.y * 64;
  const int srow = lane >> 2, scol = (lane & 3) * 8;

  f32x4 acc[4] = {};

  for (int k0 = 0; k0 < E; k0 += 64) {
#pragma unroll
    for (int jc = 0; jc < 2; jc++) {
      async16(&A[(size_t)(m0 + wv * 16 + srow) * E + k0 + jc * 32 + scol], &Asm[jc][wv * 512]);
      async16(&Bt[(size_t)(n0 + wv * 16 + srow) * E + k0 + jc * 32 + scol], &Bsm[jc][wv * 512]);
    }
    __syncthreads();
#pragma unroll
    for (int jc = 0; jc < 2; jc++) {
      bf16x8 af = *(const bf16x8*)&Asm[jc][(wv * 16 + l16) * 32 + quad * 8];
#pragma unroll
      for (int ni = 0; ni < 4; ni++) {
        bf16x8 bfr = *(const bf16x8*)&Bsm[jc][(ni * 16 + l16) * 32 + quad * 8];
        acc[ni] = MFMA(af, bfr, acc[ni]);
      }
    }
    __syncthreads();
  }

  const int row0 = m0 + wv * 16 + quad * 4;
#pragma unroll
  for (int ni = 0; ni < 4; ni++) {
    const int col = n0 + ni * 16 + l16;
    const float bv = bias[col];
#pragma unroll
    for (int r = 0; r < 4; r++)
      C[(size_t)(row0 + r) * E + col] = acc[ni][r] + bv;
  }
}

// ---------------------------------------------------------------------------
// Launch
// ---------------------------------------------------------------------------
extern "C" void kernel_launch(void* const* d_in, const int* in_sizes, int n_in,
                              void* d_out, int out_size, void* d_ws, size_t ws_size,
                              hipStream_t stream) {
  (void)in_sizes; (void)n_in; (void)out_size; (void)ws_size;
  const float* q_in = (const float*)d_in[0];
  const float* k_in = (const float*)d_in[1];
  const float* v_in = (const float*)d_in[2];
  const float* W_q  = (const float*)d_in[3];
  const float* b_q  = (const float*)d_in[4];
  const float* W_k  = (const float*)d_in[5];
  const float* b_k  = (const float*)d_in[6];
  const float* W_v  = (const float*)d_in[7];
  const float* b_v  = (const float*)d_in[8];
  const float* W_o  = (const float*)d_in[9];
  const float* b_o  = (const float*)d_in[10];

  const size_t SE2 = (size_t)S * E * 2;   // bf16 [S][E] bytes
  const size_t EE2 = (size_t)E * E * 2;
  char* ws = (char*)d_ws;
  bf16* qb  = (bf16*)(ws);                    // dead after gemm128 -> Op1
  bf16* kb  = (bf16*)(ws + SE2);              // dead after gemm128 -> Op2
  bf16* vb  = (bf16*)(ws + 2 * SE2);          // dead after gemm128 -> Op3
  bf16* WqT = (bf16*)(ws + 3 * SE2);          // dead after gemm128 -> Lp
  bf16* WkT = (bf16*)(ws + 3 * SE2 + EE2);
  bf16* WvT = (bf16*)(ws + 3 * SE2 + 2 * EE2);
  bf16* WoT = (bf16*)(ws + 3 * SE2 + 3 * EE2);
  bf16* Qh  = (bf16*)(ws + 3 * SE2 + 4 * EE2);
  bf16* Kf  = (bf16*)(ws + 4 * SE2 + 4 * EE2);
  bf16* Vf  = (bf16*)(ws + 5 * SE2 + 4 * EE2);
  bf16* Obf = (bf16*)(ws + 6 * SE2 + 4 * EE2);  // also Op0
  bf16* Op1 = qb;
  bf16* Op2 = kb;
  bf16* Op3 = vb;
  float* Lp = (float*)WqT;                    // [4][NH][S] fp32 = 786 KB < EE2
  // total ws: 7*SE2 + 4*EE2 = 48,758,784 bytes

  prologue<<<dim3(2304 + 3 * 3072), 256, 0, stream>>>(
      q_in, k_in, v_in, W_q, W_k, W_v, W_o, qb, kb, vb, WqT, WkT, WvT, WoT);

  gemm128<<<dim3(S / 128, E / 128, 3), 256, 0, stream>>>(
      qb, kb, vb, WqT, WkT, WvT, b_q, b_k, b_v, Qh, Kf, Vf);

  attn<<<dim3(S / 256, NH, KSPLIT), 256, 0, stream>>>(Qh, Kf, Vf, Obf, Op1, Op2, Op3, Lp);

  combine<<<dim3(S * E / 2048), 256, 0, stream>>>(Obf, Op1, Op2, Op3, Lp, Obf);

  gemm64<<<dim3(S / 64, E / 64), 256, 0, stream>>>(Obf, WoT, b_o, (float*)d_out);
}